// Round 3
// baseline (186.607 us; speedup 1.0000x reference)
//
#include <hip/hip_runtime.h>
#include <hip/hip_fp16.h>

// TriLinear 3D-LUT apply: lut (3,33,33,33) f32, img (4,3,1080,1920) f32
// -> out (4,3,1080,1920) f32.
//
// History:
//  R1: LDS-packed LUT, 97 us — latency-bound, serialized gathers (VGPR=64).
//  R3: ILP restructure + img prefetch + persistent blocks -> kernel < 59 us.
//  R4: prepass-quantized LUT + dwordx4 LDS staging -> total 183.1 us.
//  R5: byte LUT + v_perm pair-decode + pk-f16 lerps -> 181.7 us (1024 thr,
//      4-px, no pipeline, 16 waves/CU). NOT VALU-bound; latency-bound.
//  R6: 2-deep pipeline @ BLOCK=512 -> 182.3 us (8 waves/CU too few).
//  R7: BLOCK=768 (12 waves/CU) + global_load_lds staging -> 177.6 us.
//  R8: BLOCK=1024 with 2-px units -> 179.8 us (FAILED: occupancy gain eaten
//      by 2x per-pixel overhead; finer stages shorten the VALU runway).
//  R9 (this): BLOCK=1024 + 4-px units + 2-deep pipeline — the untested
//      corner. Structurally requires VGPR<=128 (16 waves, 1 block/CU).
//      Persistent state recount: fg[2]=82 + im[2]=26 + loop ~8 = ~116, fits
//      if transients overlap; makeFrag now packs fractions BEFORE issuing
//      gathers so fx/fy temps die before the 16 ds_read2 go out (lower
//      transient peak than the ~140 estimate that killed this config).
//      Failure signature = spill -> scratch traffic -> regression >=182.

namespace {
constexpr int D_    = 33;
constexpr int D2_   = D_ * D_;        // 1089
constexpr int LUT_N = D_ * D_ * D_;   // 35937
constexpr int HW    = 1080 * 1920;    // 2073600
constexpr int QPB   = HW / 4;         // 518400 quads per (batch) plane
constexpr int NQUADS = 4 * QPB;       // 2073600
constexpr int BLOCK = 1024;
constexpr int GRID  = 256;            // 1 persistent block per CU
constexpr int TSTRIDE = GRID * BLOCK; // 262144 -> ~7.9 iters/thread
}

typedef float v4f  __attribute__((ext_vector_type(4)));
typedef unsigned int v4u __attribute__((ext_vector_type(4)));

__device__ __forceinline__ unsigned int quant3(float r, float g, float b) {
    unsigned int qr = (unsigned int)(fminf(fmaxf(r, 0.f), 1.f) * 255.f + 0.5f);
    unsigned int qg = (unsigned int)(fminf(fmaxf(g, 0.f), 1.f) * 255.f + 0.5f);
    unsigned int qb = (unsigned int)(fminf(fmaxf(b, 0.f), 1.f) * 255.f + 0.5f);
    return qr | (qg << 8) | (qb << 16);
}

// ---- pre-pass: quantize + byte-pack the LUT into d_ws (LUT_N dwords) ----
__global__ __launch_bounds__(256)
void quantize_lut_kernel(const float* __restrict__ lut,
                         unsigned int* __restrict__ packed) {
    int i = blockIdx.x * 256 + threadIdx.x;
    if (i < LUT_N)
        packed[i] = quant3(lut[i], lut[i + LUT_N], lut[i + 2 * LUT_N]);
}

struct Img  { v4f x, y, z; int base; };
struct Frag {
    unsigned int cc[4][8];
    __half2 fxh[2], fyh[2];
    float fz[4];
    int base;
};

__device__ __forceinline__ void loadImg(const float* __restrict__ img, int q,
                                        Img& im) {
    int b  = q / QPB;
    int r4 = q - b * QPB;
    im.base = b * 3 * HW + r4 * 4;
    im.x = __builtin_nontemporal_load((const v4f*)(img + im.base));
    im.y = __builtin_nontemporal_load((const v4f*)(img + im.base + HW));
    im.z = __builtin_nontemporal_load((const v4f*)(img + im.base + 2 * HW));
}

// stage1 (indices/fractions) + issue all 16 LDS gather-pairs for one quad.
// Fraction packing happens BEFORE the gather loop so fx/fy f32 temps are dead
// by the time the 16 ds_read2 are issued (lower transient VGPR peak).
__device__ __forceinline__ void makeFrag(const unsigned int* __restrict__ slut,
                                         const Img& im, Frag& f) {
    f.base = im.base;
    float fx[4], fy[4];
    int bidx[4];
#pragma unroll
    for (int j = 0; j < 4; ++j) {
        float px = im.x[j] * 32.f;
        float py = im.y[j] * 32.f;
        float pz = im.z[j] * 32.f;
        int ix = (int)px, iy = (int)py, iz = (int)pz;
        fx[j]   = px - (float)ix;
        fy[j]   = py - (float)iy;
        f.fz[j] = pz - (float)iz;
        bidx[j] = iz * D2_ + iy * D_ + ix;
    }
    f.fxh[0] = __floats2half2_rn(fx[0], fx[1]);
    f.fxh[1] = __floats2half2_rn(fx[2], fx[3]);
    f.fyh[0] = __floats2half2_rn(fy[0], fy[1]);
    f.fyh[1] = __floats2half2_rn(fy[2], fy[3]);
#pragma unroll
    for (int j = 0; j < 4; ++j) {
        int b0 = bidx[j];
        int b1 = b0 + D2_;
        f.cc[j][0] = slut[b0];        f.cc[j][1] = slut[b0 + 1];
        f.cc[j][2] = slut[b0 + D_];   f.cc[j][3] = slut[b0 + D_ + 1];
        f.cc[j][4] = slut[b1];        f.cc[j][5] = slut[b1 + 1];
        f.cc[j][6] = slut[b1 + D_];   f.cc[j][7] = slut[b1 + D_ + 1];
    }
}

__device__ __forceinline__ __half2 lerp2(__half2 lo, __half2 hi, __half2 fr) {
    return __hfma2(fr, __hsub2(hi, lo), lo);
}

// pk-f16 blend of one 4-px quad + nontemporal store
__device__ __forceinline__ void blendStore(const Frag& f,
                                           float* __restrict__ out) {
    float outv[3][4];
#pragma unroll
    for (int p = 0; p < 2; ++p) {
        const int j0 = 2 * p, j1 = 2 * p + 1;
        __half2 fhx = f.fxh[p];
        __half2 fhy = f.fyh[p];
        const float fz0 = f.fz[j0], fz1 = f.fz[j1];
#pragma unroll
        for (int c = 0; c < 3; ++c) {
            // dst byte0 = cc[j0] byte c (sel 4+c), byte1 = 0 (sel 0x0C),
            // dst byte2 = cc[j1] byte c (sel c),   byte3 = 0 (sel 0x0C)
            const unsigned int sel = 0x0C000C04u | ((unsigned)c << 16) | (unsigned)c;
            __half2 h[8];
#pragma unroll
            for (int k = 0; k < 8; ++k) {
                union { unsigned int u; __half2 h2; } t;
                t.u = __builtin_amdgcn_perm(f.cc[j0][k], f.cc[j1][k], sel) | 0x5C005C00u;
                h[k] = t.h2;   // {256 + n_j0/4, 256 + n_j1/4} exactly in f16
            }
            __half2 x00 = lerp2(h[0], h[1], fhx);
            __half2 x01 = lerp2(h[2], h[3], fhx);
            __half2 x10 = lerp2(h[4], h[5], fhx);
            __half2 x11 = lerp2(h[6], h[7], fhx);
            __half2 y0  = lerp2(x00, x01, fhy);
            __half2 y1  = lerp2(x10, x11, fhy);
            float y0a = __low2float(y0), y0b = __high2float(y0);
            float y1a = __low2float(y1), y1b = __high2float(y1);
            float za = fmaf(fz0, y1a - y0a, y0a);
            float zb = fmaf(fz1, y1b - y0b, y0b);
            outv[c][j0] = fmaf(za, 4.0f / 255.0f, -1024.0f / 255.0f);
            outv[c][j1] = fmaf(zb, 4.0f / 255.0f, -1024.0f / 255.0f);
        }
    }
    v4f ro = {outv[0][0], outv[0][1], outv[0][2], outv[0][3]};
    v4f go = {outv[1][0], outv[1][1], outv[1][2], outv[1][3]};
    v4f bo = {outv[2][0], outv[2][1], outv[2][2], outv[2][3]};
    __builtin_nontemporal_store(ro, (v4f*)(out + f.base));
    __builtin_nontemporal_store(go, (v4f*)(out + f.base + HW));
    __builtin_nontemporal_store(bo, (v4f*)(out + f.base + 2 * HW));
}

template <bool PACKED>
__global__ __launch_bounds__(BLOCK, 4)
void trilut_kernel(const float* __restrict__ lut,
                   const unsigned int* __restrict__ packed,
                   const float* __restrict__ img,
                   float* __restrict__ out) {
    __shared__ unsigned int slut[LUT_N];   // 143748 B -> 1 block/CU, 16 waves

    Img  im0, im1;
    Frag fg0, fg1;

    // prologue: img loads for iter 0 and 1 issued BEFORE LUT staging so their
    // HBM latency hides under the staging DMA + barrier drain.
    int q0 = blockIdx.x * BLOCK + threadIdx.x;   // < 262144 < NQUADS always
    loadImg(img, q0, im0);
    int q1 = q0 + TSTRIDE;
    bool v1 = q1 < NQUADS;
    if (v1) loadImg(img, q1, im1);

    if (PACKED) {
        // global -> LDS DMA, 16B per lane per issue; destination is linear
        // (wave-uniform base + lane*16), which matches this layout exactly.
        constexpr int NCH = LUT_N / 4;     // 8984 16B chunks + 1 tail dword
        const int lane = threadIdx.x & 63;
        for (int c = threadIdx.x; c < NCH; c += BLOCK) {
            const unsigned int* gsrc = packed + c * 4;
            unsigned int* ldst = slut + (c - lane) * 4;   // wave-uniform base
            __builtin_amdgcn_global_load_lds(
                (const __attribute__((address_space(1))) unsigned int*)gsrc,
                (__attribute__((address_space(3))) unsigned int*)ldst,
                16, 0, 0);
        }
        if (threadIdx.x == 0) slut[LUT_N - 1] = packed[LUT_N - 1];
    } else {
        for (int i = threadIdx.x; i < LUT_N; i += BLOCK)
            slut[i] = quant3(lut[i], lut[i + LUT_N], lut[i + 2 * LUT_N]);
    }
    __syncthreads();   // drains vmcnt(0): staging DMA + im0/im1 all complete

    makeFrag(slut, im0, fg0);              // gathers for iter 0 in flight

    // steady state at body top (parity s): fg[s] gathered, im[s^1] holds
    // img for the next iter, load target im[s] is free.
    while (true) {
        {   // s = 0: blend fg0; produce fg1 from im1; load n+2 -> im0
            int q2 = q1 + TSTRIDE; bool v2 = q2 < NQUADS;
            if (v2) loadImg(img, q2, im0);
            if (v1) makeFrag(slut, im1, fg1);
            blendStore(fg0, out);
            if (!v1) return;
            q1 = q2; v1 = v2;
        }
        {   // s = 1: blend fg1; produce fg0 from im0; load n+2 -> im1
            int q2 = q1 + TSTRIDE; bool v2 = q2 < NQUADS;
            if (v2) loadImg(img, q2, im1);
            if (v1) makeFrag(slut, im0, fg0);
            blendStore(fg1, out);
            if (!v1) return;
            q1 = q2; v1 = v2;
        }
    }
}

extern "C" void kernel_launch(void* const* d_in, const int* in_sizes, int n_in,
                              void* d_out, int out_size, void* d_ws, size_t ws_size,
                              hipStream_t stream) {
    const float* lut = (const float*)d_in[0];
    const float* img = (const float*)d_in[1];
    float* out = (float*)d_out;

    if (ws_size >= (size_t)LUT_N * sizeof(unsigned int)) {
        unsigned int* packed = (unsigned int*)d_ws;
        quantize_lut_kernel<<<(LUT_N + 255) / 256, 256, 0, stream>>>(lut, packed);
        trilut_kernel<true><<<GRID, BLOCK, 0, stream>>>(lut, packed, img, out);
    } else {
        trilut_kernel<false><<<GRID, BLOCK, 0, stream>>>(lut, nullptr, img, out);
    }
}

// Round 4
// 180.172 us; speedup vs baseline: 1.0357x; 1.0357x over previous
//
#include <hip/hip_runtime.h>
#include <hip/hip_fp16.h>

// TriLinear 3D-LUT apply: lut (3,33,33,33) f32, img (4,3,1080,1920) f32
// -> out (4,3,1080,1920) f32.
//
// History:
//  R1: LDS-packed LUT, 97 us — latency-bound, serialized gathers (VGPR=64).
//  R3: ILP restructure + img prefetch + persistent blocks -> kernel < 59 us.
//  R4: prepass-quantized LUT + dwordx4 LDS staging -> total 183.1 us.
//  R5: byte LUT + v_perm pair-decode + pk-f16 lerps -> 181.7 us (1024 thr,
//      4-px, no pipeline). NOT VALU-bound; latency-bound.
//  R6: 2-deep pipeline @ BLOCK=512 -> 182.3 us (8 waves/CU too few).
//  R7: BLOCK=768 (12 waves/CU) + global_load_lds staging -> 177.6 us. BEST.
//  R8: BLOCK=1024 + 2-px units -> 179.8 us (unit overhead ate occupancy win).
//  R9: BLOCK=1024 + 4-px + pipeline -> 186.6 us (VGPR spill as predicted).
//      => occupancy ladder ends at 768/12 waves; revert to R7 config.
//  R10 (this): fix the lgkmcnt-encoding stall in the pipeline.
//      makeFrag issues 16 ds_read2 then blend consumes the PREVIOUS frag;
//      16 outstanding > lgkmcnt max 15 forces the compiler to emit
//      lgkmcnt(15), which waits on the FIRST of the just-issued gathers
//      (~120cy, in-order LDS return) — a structural stall every half-iter.
//      Split into 8-op halves interleaved with blend halves:
//        gather(next,h0) -> blend(cur,p0) -> gather(next,h1) -> blend(cur,p1)
//      Every forced wait now covers gathers issued >=1 blend-half (~150cy)
//      earlier -> complete -> no stall. Same registers, pure reorder.

namespace {
constexpr int D_    = 33;
constexpr int D2_   = D_ * D_;        // 1089
constexpr int LUT_N = D_ * D_ * D_;   // 35937
constexpr int HW    = 1080 * 1920;    // 2073600
constexpr int QPB   = HW / 4;         // 518400 quads per (batch) plane
constexpr int NQUADS = 4 * QPB;       // 2073600
constexpr int BLOCK = 768;
constexpr int GRID  = 256;            // 1 persistent block per CU
constexpr int TSTRIDE = GRID * BLOCK; // 196608 -> ~10.5 iters/thread
}

typedef float v4f  __attribute__((ext_vector_type(4)));
typedef unsigned int v4u __attribute__((ext_vector_type(4)));

__device__ __forceinline__ unsigned int quant3(float r, float g, float b) {
    unsigned int qr = (unsigned int)(fminf(fmaxf(r, 0.f), 1.f) * 255.f + 0.5f);
    unsigned int qg = (unsigned int)(fminf(fmaxf(g, 0.f), 1.f) * 255.f + 0.5f);
    unsigned int qb = (unsigned int)(fminf(fmaxf(b, 0.f), 1.f) * 255.f + 0.5f);
    return qr | (qg << 8) | (qb << 16);
}

// ---- pre-pass: quantize + byte-pack the LUT into d_ws (LUT_N dwords) ----
__global__ __launch_bounds__(256)
void quantize_lut_kernel(const float* __restrict__ lut,
                         unsigned int* __restrict__ packed) {
    int i = blockIdx.x * 256 + threadIdx.x;
    if (i < LUT_N)
        packed[i] = quant3(lut[i], lut[i + LUT_N], lut[i + 2 * LUT_N]);
}

struct Img  { v4f x, y, z; int base; };
struct Frag {
    unsigned int cc[4][8];
    __half2 fxh[2], fyh[2];
    float fz[4];
    int base;
};

__device__ __forceinline__ void loadImg(const float* __restrict__ img, int q,
                                        Img& im) {
    int b  = q / QPB;
    int r4 = q - b * QPB;
    im.base = b * 3 * HW + r4 * 4;
    im.x = __builtin_nontemporal_load((const v4f*)(img + im.base));
    im.y = __builtin_nontemporal_load((const v4f*)(img + im.base + HW));
    im.z = __builtin_nontemporal_load((const v4f*)(img + im.base + 2 * HW));
}

// stage1: indices + packed fractions for all 4 px (no LDS traffic)
__device__ __forceinline__ void makeIdx(const Img& im, Frag& f, int bidx[4]) {
    f.base = im.base;
    float fx[4], fy[4];
#pragma unroll
    for (int j = 0; j < 4; ++j) {
        float px = im.x[j] * 32.f;
        float py = im.y[j] * 32.f;
        float pz = im.z[j] * 32.f;
        int ix = (int)px, iy = (int)py, iz = (int)pz;
        fx[j]   = px - (float)ix;
        fy[j]   = py - (float)iy;
        f.fz[j] = pz - (float)iz;
        bidx[j] = iz * D2_ + iy * D_ + ix;
    }
    f.fxh[0] = __floats2half2_rn(fx[0], fx[1]);
    f.fxh[1] = __floats2half2_rn(fx[2], fx[3]);
    f.fyh[0] = __floats2half2_rn(fy[0], fy[1]);
    f.fyh[1] = __floats2half2_rn(fy[2], fy[3]);
}

// issue the 8 ds_read2 for pixels {2p, 2p+1}
__device__ __forceinline__ void gatherHalf(const unsigned int* __restrict__ slut,
                                           const int bidx[4], Frag& f, int p) {
#pragma unroll
    for (int j = 2 * p; j < 2 * p + 2; ++j) {
        int b0 = bidx[j];
        int b1 = b0 + D2_;
        f.cc[j][0] = slut[b0];        f.cc[j][1] = slut[b0 + 1];
        f.cc[j][2] = slut[b0 + D_];   f.cc[j][3] = slut[b0 + D_ + 1];
        f.cc[j][4] = slut[b1];        f.cc[j][5] = slut[b1 + 1];
        f.cc[j][6] = slut[b1 + D_];   f.cc[j][7] = slut[b1 + D_ + 1];
    }
}

__device__ __forceinline__ __half2 lerp2(__half2 lo, __half2 hi, __half2 fr) {
    return __hfma2(fr, __hsub2(hi, lo), lo);
}

// pk-f16 blend of pixel pair {2p, 2p+1} of one quad
__device__ __forceinline__ void blendHalf(const Frag& f, int p,
                                          float outv[3][4]) {
    const int j0 = 2 * p, j1 = 2 * p + 1;
    const __half2 fhx = f.fxh[p];
    const __half2 fhy = f.fyh[p];
    const float fz0 = f.fz[j0], fz1 = f.fz[j1];
#pragma unroll
    for (int c = 0; c < 3; ++c) {
        // dst byte0 = cc[j0] byte c (sel 4+c), byte1 = 0 (sel 0x0C),
        // dst byte2 = cc[j1] byte c (sel c),   byte3 = 0 (sel 0x0C)
        const unsigned int sel = 0x0C000C04u | ((unsigned)c << 16) | (unsigned)c;
        __half2 h[8];
#pragma unroll
        for (int k = 0; k < 8; ++k) {
            union { unsigned int u; __half2 h2; } t;
            t.u = __builtin_amdgcn_perm(f.cc[j0][k], f.cc[j1][k], sel) | 0x5C005C00u;
            h[k] = t.h2;   // {256 + n_j0/4, 256 + n_j1/4} exactly in f16
        }
        __half2 x00 = lerp2(h[0], h[1], fhx);
        __half2 x01 = lerp2(h[2], h[3], fhx);
        __half2 x10 = lerp2(h[4], h[5], fhx);
        __half2 x11 = lerp2(h[6], h[7], fhx);
        __half2 y0  = lerp2(x00, x01, fhy);
        __half2 y1  = lerp2(x10, x11, fhy);
        float y0a = __low2float(y0), y0b = __high2float(y0);
        float y1a = __low2float(y1), y1b = __high2float(y1);
        float za = fmaf(fz0, y1a - y0a, y0a);
        float zb = fmaf(fz1, y1b - y0b, y0b);
        outv[c][j0] = fmaf(za, 4.0f / 255.0f, -1024.0f / 255.0f);
        outv[c][j1] = fmaf(zb, 4.0f / 255.0f, -1024.0f / 255.0f);
    }
}

__device__ __forceinline__ void storeQuad(const Frag& f,
                                          const float outv[3][4],
                                          float* __restrict__ out) {
    v4f ro = {outv[0][0], outv[0][1], outv[0][2], outv[0][3]};
    v4f go = {outv[1][0], outv[1][1], outv[1][2], outv[1][3]};
    v4f bo = {outv[2][0], outv[2][1], outv[2][2], outv[2][3]};
    __builtin_nontemporal_store(ro, (v4f*)(out + f.base));
    __builtin_nontemporal_store(go, (v4f*)(out + f.base + HW));
    __builtin_nontemporal_store(bo, (v4f*)(out + f.base + 2 * HW));
}

template <bool PACKED>
__global__ __launch_bounds__(BLOCK, 3)
void trilut_kernel(const float* __restrict__ lut,
                   const unsigned int* __restrict__ packed,
                   const float* __restrict__ img,
                   float* __restrict__ out) {
    __shared__ unsigned int slut[LUT_N];   // 143748 B -> 1 block/CU, 12 waves

    Img  im0, im1;
    Frag fg0, fg1;

    // prologue: img loads for iter 0 and 1 issued BEFORE LUT staging so their
    // HBM latency hides under the staging DMA + barrier drain.
    int q0 = blockIdx.x * BLOCK + threadIdx.x;   // < 196608 < NQUADS always
    loadImg(img, q0, im0);
    int q1 = q0 + TSTRIDE;
    bool v1 = q1 < NQUADS;                       // block-uniform (140*768 cut)
    if (v1) loadImg(img, q1, im1);

    if (PACKED) {
        // global -> LDS DMA, 16B per lane per issue; destination is linear
        // (wave-uniform base + lane*16), which matches this layout exactly.
        constexpr int NCH = LUT_N / 4;     // 8984 16B chunks + 1 tail dword
        const int lane = threadIdx.x & 63;
        for (int c = threadIdx.x; c < NCH; c += BLOCK) {
            const unsigned int* gsrc = packed + c * 4;
            unsigned int* ldst = slut + (c - lane) * 4;   // wave-uniform base
            __builtin_amdgcn_global_load_lds(
                (const __attribute__((address_space(1))) unsigned int*)gsrc,
                (__attribute__((address_space(3))) unsigned int*)ldst,
                16, 0, 0);
        }
        if (threadIdx.x == 0) slut[LUT_N - 1] = packed[LUT_N - 1];
    } else {
        for (int i = threadIdx.x; i < LUT_N; i += BLOCK)
            slut[i] = quant3(lut[i], lut[i + LUT_N], lut[i + 2 * LUT_N]);
    }
    __syncthreads();   // drains vmcnt(0): staging DMA + im0/im1 all complete

    {   // gathers for iter 0 fully in flight before the loop
        int bidx[4];
        makeIdx(im0, fg0, bidx);
        gatherHalf(slut, bidx, fg0, 0);
        gatherHalf(slut, bidx, fg0, 1);
    }

    // steady state (parity s): fg[s] gathered, im[s^1] holds next img.
    // Interleave: gather(next,h0) -> blend(cur,p0) -> gather(next,h1)
    //          -> blend(cur,p1) -> store. Max encodable waits only.
    while (true) {
        {   // s = 0: blend fg0; produce fg1 from im1; load n+2 -> im0
            int q2 = q1 + TSTRIDE; bool v2 = q2 < NQUADS;
            if (v2) loadImg(img, q2, im0);
            int bidx[4];
            float outv[3][4];
            if (v1) { makeIdx(im1, fg1, bidx); gatherHalf(slut, bidx, fg1, 0); }
            blendHalf(fg0, 0, outv);
            if (v1) gatherHalf(slut, bidx, fg1, 1);
            blendHalf(fg0, 1, outv);
            storeQuad(fg0, outv, out);
            if (!v1) return;
            q1 = q2; v1 = v2;
        }
        {   // s = 1: blend fg1; produce fg0 from im0; load n+2 -> im1
            int q2 = q1 + TSTRIDE; bool v2 = q2 < NQUADS;
            if (v2) loadImg(img, q2, im1);
            int bidx[4];
            float outv[3][4];
            if (v1) { makeIdx(im0, fg0, bidx); gatherHalf(slut, bidx, fg0, 0); }
            blendHalf(fg1, 0, outv);
            if (v1) gatherHalf(slut, bidx, fg0, 1);
            blendHalf(fg1, 1, outv);
            storeQuad(fg1, outv, out);
            if (!v1) return;
            q1 = q2; v1 = v2;
        }
    }
}

extern "C" void kernel_launch(void* const* d_in, const int* in_sizes, int n_in,
                              void* d_out, int out_size, void* d_ws, size_t ws_size,
                              hipStream_t stream) {
    const float* lut = (const float*)d_in[0];
    const float* img = (const float*)d_in[1];
    float* out = (float*)d_out;

    if (ws_size >= (size_t)LUT_N * sizeof(unsigned int)) {
        unsigned int* packed = (unsigned int*)d_ws;
        quantize_lut_kernel<<<(LUT_N + 255) / 256, 256, 0, stream>>>(lut, packed);
        trilut_kernel<true><<<GRID, BLOCK, 0, stream>>>(lut, packed, img, out);
    } else {
        trilut_kernel<false><<<GRID, BLOCK, 0, stream>>>(lut, nullptr, img, out);
    }
}

// Round 5
// 178.752 us; speedup vs baseline: 1.0439x; 1.0079x over previous
//
#include <hip/hip_runtime.h>
#include <hip/hip_fp16.h>

// TriLinear 3D-LUT apply: lut (3,33,33,33) f32, img (4,3,1080,1920) f32
// -> out (4,3,1080,1920) f32.
//
// History:
//  R1: LDS-packed LUT, 97 us — latency-bound, serialized gathers (VGPR=64).
//  R3: ILP restructure + img prefetch + persistent blocks -> kernel < 59 us.
//  R4: prepass-quantized LUT + dwordx4 LDS staging -> total 183.1 us.
//  R5: byte LUT + v_perm pair-decode + pk-f16 lerps -> 181.7 us. NOT
//      VALU-bound; latency-bound.
//  R6: 2-deep pipeline @ BLOCK=512 -> 182.3 us (8 waves/CU too few).
//  R7: BLOCK=768 (12 waves/CU) + global_load_lds staging -> 177.6 us. BEST.
//  R8: BLOCK=1024 + 2-px units -> 179.8 us (unit overhead ate occupancy win).
//  R9: BLOCK=1024 + 4-px + pipeline -> 186.6 us (VGPR spill as predicted).
//  R10: split gather/blend interleave (lgkmcnt-encoding theory) -> 180.2 us.
//      Falsified: intra-iteration order doesn't matter.
//  R11 (this): R7 exactly + WAVE DE-PHASING.
//      Model: per-SIMD VALU work is ~1.9k cyc/round but wall is ~12k cyc;
//      all waves stall together. LDS (~15us) adds to HBM (~36us) instead of
//      overlapping: waves start in lockstep, all 12 issue their 16-deep
//      ds_read2 burst in the same window -> LDS queue backs up -> issue
//      stalls -> then all blend while LDS idles. No barrier after staging,
//      so a one-time skew persists: wave w sleeps w*~512 cyc after
//      __syncthreads so gather bursts tile the iteration round instead of
//      colliding. Failure criterion: total within +-2us of 177.6 -> theory
//      falsified, next probe = waitcnt chaining via inline asm.

namespace {
constexpr int D_    = 33;
constexpr int D2_   = D_ * D_;        // 1089
constexpr int LUT_N = D_ * D_ * D_;   // 35937
constexpr int HW    = 1080 * 1920;    // 2073600
constexpr int QPB   = HW / 4;         // 518400 quads per (batch) plane
constexpr int NQUADS = 4 * QPB;       // 2073600
constexpr int BLOCK = 768;
constexpr int GRID  = 256;            // 1 persistent block per CU
constexpr int TSTRIDE = GRID * BLOCK; // 196608 -> ~10.5 iters/thread
}

typedef float v4f  __attribute__((ext_vector_type(4)));
typedef unsigned int v4u __attribute__((ext_vector_type(4)));

__device__ __forceinline__ unsigned int quant3(float r, float g, float b) {
    unsigned int qr = (unsigned int)(fminf(fmaxf(r, 0.f), 1.f) * 255.f + 0.5f);
    unsigned int qg = (unsigned int)(fminf(fmaxf(g, 0.f), 1.f) * 255.f + 0.5f);
    unsigned int qb = (unsigned int)(fminf(fmaxf(b, 0.f), 1.f) * 255.f + 0.5f);
    return qr | (qg << 8) | (qb << 16);
}

// ---- pre-pass: quantize + byte-pack the LUT into d_ws (LUT_N dwords) ----
__global__ __launch_bounds__(256)
void quantize_lut_kernel(const float* __restrict__ lut,
                         unsigned int* __restrict__ packed) {
    int i = blockIdx.x * 256 + threadIdx.x;
    if (i < LUT_N)
        packed[i] = quant3(lut[i], lut[i + LUT_N], lut[i + 2 * LUT_N]);
}

struct Img  { v4f x, y, z; int base; };
struct Frag {
    unsigned int cc[4][8];
    __half2 fxh[2], fyh[2];
    float fz[4];
    int base;
};

__device__ __forceinline__ void loadImg(const float* __restrict__ img, int q,
                                        Img& im) {
    int b  = q / QPB;
    int r4 = q - b * QPB;
    im.base = b * 3 * HW + r4 * 4;
    im.x = __builtin_nontemporal_load((const v4f*)(img + im.base));
    im.y = __builtin_nontemporal_load((const v4f*)(img + im.base + HW));
    im.z = __builtin_nontemporal_load((const v4f*)(img + im.base + 2 * HW));
}

// stage1 (indices/fractions) + issue all 16 LDS gathers for one 4-px quad
__device__ __forceinline__ void makeFrag(const unsigned int* __restrict__ slut,
                                         const Img& im, Frag& f) {
    f.base = im.base;
    float fx[4], fy[4];
    int bidx[4];
#pragma unroll
    for (int j = 0; j < 4; ++j) {
        float px = im.x[j] * 32.f;
        float py = im.y[j] * 32.f;
        float pz = im.z[j] * 32.f;
        int ix = (int)px, iy = (int)py, iz = (int)pz;
        fx[j]   = px - (float)ix;
        fy[j]   = py - (float)iy;
        f.fz[j] = pz - (float)iz;
        bidx[j] = iz * D2_ + iy * D_ + ix;
    }
#pragma unroll
    for (int j = 0; j < 4; ++j) {
        int b0 = bidx[j];
        int b1 = b0 + D2_;
        f.cc[j][0] = slut[b0];        f.cc[j][1] = slut[b0 + 1];
        f.cc[j][2] = slut[b0 + D_];   f.cc[j][3] = slut[b0 + D_ + 1];
        f.cc[j][4] = slut[b1];        f.cc[j][5] = slut[b1 + 1];
        f.cc[j][6] = slut[b1 + D_];   f.cc[j][7] = slut[b1 + D_ + 1];
    }
    f.fxh[0] = __floats2half2_rn(fx[0], fx[1]);
    f.fxh[1] = __floats2half2_rn(fx[2], fx[3]);
    f.fyh[0] = __floats2half2_rn(fy[0], fy[1]);
    f.fyh[1] = __floats2half2_rn(fy[2], fy[3]);
}

__device__ __forceinline__ __half2 lerp2(__half2 lo, __half2 hi, __half2 fr) {
    return __hfma2(fr, __hsub2(hi, lo), lo);
}

// pk-f16 blend of one 4-px quad + nontemporal store
__device__ __forceinline__ void blendStore(const Frag& f,
                                           float* __restrict__ out) {
    float outv[3][4];
#pragma unroll
    for (int p = 0; p < 2; ++p) {
        const int j0 = 2 * p, j1 = 2 * p + 1;
        __half2 fhx = f.fxh[p];
        __half2 fhy = f.fyh[p];
        const float fz0 = f.fz[j0], fz1 = f.fz[j1];
#pragma unroll
        for (int c = 0; c < 3; ++c) {
            // dst byte0 = cc[j0] byte c (sel 4+c), byte1 = 0 (sel 0x0C),
            // dst byte2 = cc[j1] byte c (sel c),   byte3 = 0 (sel 0x0C)
            const unsigned int sel = 0x0C000C04u | ((unsigned)c << 16) | (unsigned)c;
            __half2 h[8];
#pragma unroll
            for (int k = 0; k < 8; ++k) {
                union { unsigned int u; __half2 h2; } t;
                t.u = __builtin_amdgcn_perm(f.cc[j0][k], f.cc[j1][k], sel) | 0x5C005C00u;
                h[k] = t.h2;   // {256 + n_j0/4, 256 + n_j1/4} exactly in f16
            }
            __half2 x00 = lerp2(h[0], h[1], fhx);
            __half2 x01 = lerp2(h[2], h[3], fhx);
            __half2 x10 = lerp2(h[4], h[5], fhx);
            __half2 x11 = lerp2(h[6], h[7], fhx);
            __half2 y0  = lerp2(x00, x01, fhy);
            __half2 y1  = lerp2(x10, x11, fhy);
            float y0a = __low2float(y0), y0b = __high2float(y0);
            float y1a = __low2float(y1), y1b = __high2float(y1);
            float za = fmaf(fz0, y1a - y0a, y0a);
            float zb = fmaf(fz1, y1b - y0b, y0b);
            outv[c][j0] = fmaf(za, 4.0f / 255.0f, -1024.0f / 255.0f);
            outv[c][j1] = fmaf(zb, 4.0f / 255.0f, -1024.0f / 255.0f);
        }
    }
    v4f ro = {outv[0][0], outv[0][1], outv[0][2], outv[0][3]};
    v4f go = {outv[1][0], outv[1][1], outv[1][2], outv[1][3]};
    v4f bo = {outv[2][0], outv[2][1], outv[2][2], outv[2][3]};
    __builtin_nontemporal_store(ro, (v4f*)(out + f.base));
    __builtin_nontemporal_store(go, (v4f*)(out + f.base + HW));
    __builtin_nontemporal_store(bo, (v4f*)(out + f.base + 2 * HW));
}

template <bool PACKED>
__global__ __launch_bounds__(BLOCK, 3)
void trilut_kernel(const float* __restrict__ lut,
                   const unsigned int* __restrict__ packed,
                   const float* __restrict__ img,
                   float* __restrict__ out) {
    __shared__ unsigned int slut[LUT_N];   // 143748 B -> 1 block/CU, 12 waves

    Img  im0, im1;
    Frag fg0, fg1;

    // prologue: img loads for iter 0 and 1 issued BEFORE LUT staging so their
    // HBM latency hides under the staging DMA + barrier drain.
    int q0 = blockIdx.x * BLOCK + threadIdx.x;   // < 196608 < NQUADS always
    loadImg(img, q0, im0);
    int q1 = q0 + TSTRIDE;
    bool v1 = q1 < NQUADS;                       // block-uniform (140*768 cut)
    if (v1) loadImg(img, q1, im1);

    if (PACKED) {
        // global -> LDS DMA, 16B per lane per issue; destination is linear
        // (wave-uniform base + lane*16), which matches this layout exactly.
        constexpr int NCH = LUT_N / 4;     // 8984 16B chunks + 1 tail dword
        const int lane = threadIdx.x & 63;
        for (int c = threadIdx.x; c < NCH; c += BLOCK) {
            const unsigned int* gsrc = packed + c * 4;
            unsigned int* ldst = slut + (c - lane) * 4;   // wave-uniform base
            __builtin_amdgcn_global_load_lds(
                (const __attribute__((address_space(1))) unsigned int*)gsrc,
                (__attribute__((address_space(3))) unsigned int*)ldst,
                16, 0, 0);
        }
        if (threadIdx.x == 0) slut[LUT_N - 1] = packed[LUT_N - 1];
    } else {
        for (int i = threadIdx.x; i < LUT_N; i += BLOCK)
            slut[i] = quant3(lut[i], lut[i + LUT_N], lut[i + 2 * LUT_N]);
    }
    __syncthreads();   // drains vmcnt(0): staging DMA + im0/im1 all complete

    // ---- wave de-phasing: last sync point was the barrier above; nothing
    // re-locks phases afterward. Wave w sleeps ~w*512 cyc so the 12 waves'
    // 16-deep ds_read2 bursts tile the iteration round instead of slamming
    // the LDS queue simultaneously. Max skew ~5.6k cyc (~half a round).
    {
        const int wid = threadIdx.x >> 6;        // wave-uniform, 0..11
        for (int i = 0; i < wid; ++i) __builtin_amdgcn_s_sleep(8);
    }

    makeFrag(slut, im0, fg0);              // gathers for iter 0 in flight

    // steady state at body top (parity s): fg[s] gathered, im[s^1] holds
    // img for the next iter, load target im[s] is free.
    while (true) {
        {   // s = 0: blend fg0; produce fg1 from im1; load n+2 -> im0
            int q2 = q1 + TSTRIDE; bool v2 = q2 < NQUADS;
            if (v2) loadImg(img, q2, im0);
            if (v1) makeFrag(slut, im1, fg1);
            blendStore(fg0, out);
            if (!v1) return;
            q1 = q2; v1 = v2;
        }
        {   // s = 1: blend fg1; produce fg0 from im0; load n+2 -> im1
            int q2 = q1 + TSTRIDE; bool v2 = q2 < NQUADS;
            if (v2) loadImg(img, q2, im1);
            if (v1) makeFrag(slut, im0, fg0);
            blendStore(fg1, out);
            if (!v1) return;
            q1 = q2; v1 = v2;
        }
    }
}

extern "C" void kernel_launch(void* const* d_in, const int* in_sizes, int n_in,
                              void* d_out, int out_size, void* d_ws, size_t ws_size,
                              hipStream_t stream) {
    const float* lut = (const float*)d_in[0];
    const float* img = (const float*)d_in[1];
    float* out = (float*)d_out;

    if (ws_size >= (size_t)LUT_N * sizeof(unsigned int)) {
        unsigned int* packed = (unsigned int*)d_ws;
        quantize_lut_kernel<<<(LUT_N + 255) / 256, 256, 0, stream>>>(lut, packed);
        trilut_kernel<true><<<GRID, BLOCK, 0, stream>>>(lut, packed, img, out);
    } else {
        trilut_kernel<false><<<GRID, BLOCK, 0, stream>>>(lut, nullptr, img, out);
    }
}

// Round 6
// 177.453 us; speedup vs baseline: 1.0516x; 1.0073x over previous
//
#include <hip/hip_runtime.h>
#include <hip/hip_fp16.h>

// TriLinear 3D-LUT apply: lut (3,33,33,33) f32, img (4,3,1080,1920) f32
// -> out (4,3,1080,1920) f32.
//
// History:
//  R1: LDS-packed LUT, 97 us — latency-bound, serialized gathers (VGPR=64).
//  R3: ILP restructure + img prefetch + persistent blocks -> kernel < 59 us.
//  R4: prepass-quantized LUT + dwordx4 LDS staging -> total 183.1 us.
//  R5: byte LUT + v_perm pair-decode + pk-f16 lerps -> 181.7 us. NOT
//      VALU-bound; latency-bound.
//  R6: 2-deep pipeline @ BLOCK=512 -> 182.3 us (8 waves/CU too few).
//  R7: BLOCK=768 (12 waves/CU) + global_load_lds staging -> 177.6 us. BEST.
//  R8: BLOCK=1024 + 2-px units -> 179.8 us (unit overhead ate occupancy win).
//  R9: BLOCK=1024 + 4-px + pipeline -> 186.6 us (VGPR spill as predicted).
//  R10: split gather/blend interleave (lgkmcnt theory) -> 180.2 us. Null.
//  R11: wave de-phasing via s_sleep skew -> 178.8 us. Null (phase-lock
//      theory falsified; LDS+HBM additivity is not a lockstep artifact).
//  R12 (this): exact R7 + s_setprio(1) around the blend (T5).
//      Model: round = HBM(7.4k cyc) + LDS(4k cyc) additive; work terms are
//      structurally fixed (all alignment-forcing LUT layouts exceed 160KB
//      LDS; parity tricks diverge). Last untried lever: runtime wave
//      arbitration. Waves here are role-diverse (gather-phase vs
//      blend-phase); prioritizing blend-phase waves drains ready VALU work
//      first so those waves re-issue their next gather burst sooner,
//      smoothing LDS-pipe occupancy. Pure hint: no schedule/register risk.
//      Falsification: total within +-1.5us of 177.6 -> structural plateau
//      confirmed; this config is final.

namespace {
constexpr int D_    = 33;
constexpr int D2_   = D_ * D_;        // 1089
constexpr int LUT_N = D_ * D_ * D_;   // 35937
constexpr int HW    = 1080 * 1920;    // 2073600
constexpr int QPB   = HW / 4;         // 518400 quads per (batch) plane
constexpr int NQUADS = 4 * QPB;       // 2073600
constexpr int BLOCK = 768;
constexpr int GRID  = 256;            // 1 persistent block per CU
constexpr int TSTRIDE = GRID * BLOCK; // 196608 -> ~10.5 iters/thread
}

typedef float v4f  __attribute__((ext_vector_type(4)));
typedef unsigned int v4u __attribute__((ext_vector_type(4)));

__device__ __forceinline__ unsigned int quant3(float r, float g, float b) {
    unsigned int qr = (unsigned int)(fminf(fmaxf(r, 0.f), 1.f) * 255.f + 0.5f);
    unsigned int qg = (unsigned int)(fminf(fmaxf(g, 0.f), 1.f) * 255.f + 0.5f);
    unsigned int qb = (unsigned int)(fminf(fmaxf(b, 0.f), 1.f) * 255.f + 0.5f);
    return qr | (qg << 8) | (qb << 16);
}

// ---- pre-pass: quantize + byte-pack the LUT into d_ws (LUT_N dwords) ----
__global__ __launch_bounds__(256)
void quantize_lut_kernel(const float* __restrict__ lut,
                         unsigned int* __restrict__ packed) {
    int i = blockIdx.x * 256 + threadIdx.x;
    if (i < LUT_N)
        packed[i] = quant3(lut[i], lut[i + LUT_N], lut[i + 2 * LUT_N]);
}

struct Img  { v4f x, y, z; int base; };
struct Frag {
    unsigned int cc[4][8];
    __half2 fxh[2], fyh[2];
    float fz[4];
    int base;
};

__device__ __forceinline__ void loadImg(const float* __restrict__ img, int q,
                                        Img& im) {
    int b  = q / QPB;
    int r4 = q - b * QPB;
    im.base = b * 3 * HW + r4 * 4;
    im.x = __builtin_nontemporal_load((const v4f*)(img + im.base));
    im.y = __builtin_nontemporal_load((const v4f*)(img + im.base + HW));
    im.z = __builtin_nontemporal_load((const v4f*)(img + im.base + 2 * HW));
}

// stage1 (indices/fractions) + issue all 16 LDS gathers for one 4-px quad
__device__ __forceinline__ void makeFrag(const unsigned int* __restrict__ slut,
                                         const Img& im, Frag& f) {
    f.base = im.base;
    float fx[4], fy[4];
    int bidx[4];
#pragma unroll
    for (int j = 0; j < 4; ++j) {
        float px = im.x[j] * 32.f;
        float py = im.y[j] * 32.f;
        float pz = im.z[j] * 32.f;
        int ix = (int)px, iy = (int)py, iz = (int)pz;
        fx[j]   = px - (float)ix;
        fy[j]   = py - (float)iy;
        f.fz[j] = pz - (float)iz;
        bidx[j] = iz * D2_ + iy * D_ + ix;
    }
#pragma unroll
    for (int j = 0; j < 4; ++j) {
        int b0 = bidx[j];
        int b1 = b0 + D2_;
        f.cc[j][0] = slut[b0];        f.cc[j][1] = slut[b0 + 1];
        f.cc[j][2] = slut[b0 + D_];   f.cc[j][3] = slut[b0 + D_ + 1];
        f.cc[j][4] = slut[b1];        f.cc[j][5] = slut[b1 + 1];
        f.cc[j][6] = slut[b1 + D_];   f.cc[j][7] = slut[b1 + D_ + 1];
    }
    f.fxh[0] = __floats2half2_rn(fx[0], fx[1]);
    f.fxh[1] = __floats2half2_rn(fx[2], fx[3]);
    f.fyh[0] = __floats2half2_rn(fy[0], fy[1]);
    f.fyh[1] = __floats2half2_rn(fy[2], fy[3]);
}

__device__ __forceinline__ __half2 lerp2(__half2 lo, __half2 hi, __half2 fr) {
    return __hfma2(fr, __hsub2(hi, lo), lo);
}

// pk-f16 blend of one 4-px quad + nontemporal store.
// s_setprio(1) for the duration: blend-phase waves get CU-scheduler priority
// over gather-phase waves (T5; waves are role-diverse, non-lockstep).
__device__ __forceinline__ void blendStore(const Frag& f,
                                           float* __restrict__ out) {
    __builtin_amdgcn_s_setprio(1);
    float outv[3][4];
#pragma unroll
    for (int p = 0; p < 2; ++p) {
        const int j0 = 2 * p, j1 = 2 * p + 1;
        __half2 fhx = f.fxh[p];
        __half2 fhy = f.fyh[p];
        const float fz0 = f.fz[j0], fz1 = f.fz[j1];
#pragma unroll
        for (int c = 0; c < 3; ++c) {
            // dst byte0 = cc[j0] byte c (sel 4+c), byte1 = 0 (sel 0x0C),
            // dst byte2 = cc[j1] byte c (sel c),   byte3 = 0 (sel 0x0C)
            const unsigned int sel = 0x0C000C04u | ((unsigned)c << 16) | (unsigned)c;
            __half2 h[8];
#pragma unroll
            for (int k = 0; k < 8; ++k) {
                union { unsigned int u; __half2 h2; } t;
                t.u = __builtin_amdgcn_perm(f.cc[j0][k], f.cc[j1][k], sel) | 0x5C005C00u;
                h[k] = t.h2;   // {256 + n_j0/4, 256 + n_j1/4} exactly in f16
            }
            __half2 x00 = lerp2(h[0], h[1], fhx);
            __half2 x01 = lerp2(h[2], h[3], fhx);
            __half2 x10 = lerp2(h[4], h[5], fhx);
            __half2 x11 = lerp2(h[6], h[7], fhx);
            __half2 y0  = lerp2(x00, x01, fhy);
            __half2 y1  = lerp2(x10, x11, fhy);
            float y0a = __low2float(y0), y0b = __high2float(y0);
            float y1a = __low2float(y1), y1b = __high2float(y1);
            float za = fmaf(fz0, y1a - y0a, y0a);
            float zb = fmaf(fz1, y1b - y0b, y0b);
            outv[c][j0] = fmaf(za, 4.0f / 255.0f, -1024.0f / 255.0f);
            outv[c][j1] = fmaf(zb, 4.0f / 255.0f, -1024.0f / 255.0f);
        }
    }
    v4f ro = {outv[0][0], outv[0][1], outv[0][2], outv[0][3]};
    v4f go = {outv[1][0], outv[1][1], outv[1][2], outv[1][3]};
    v4f bo = {outv[2][0], outv[2][1], outv[2][2], outv[2][3]};
    __builtin_nontemporal_store(ro, (v4f*)(out + f.base));
    __builtin_nontemporal_store(go, (v4f*)(out + f.base + HW));
    __builtin_nontemporal_store(bo, (v4f*)(out + f.base + 2 * HW));
    __builtin_amdgcn_s_setprio(0);
}

template <bool PACKED>
__global__ __launch_bounds__(BLOCK, 3)
void trilut_kernel(const float* __restrict__ lut,
                   const unsigned int* __restrict__ packed,
                   const float* __restrict__ img,
                   float* __restrict__ out) {
    __shared__ unsigned int slut[LUT_N];   // 143748 B -> 1 block/CU, 12 waves

    Img  im0, im1;
    Frag fg0, fg1;

    // prologue: img loads for iter 0 and 1 issued BEFORE LUT staging so their
    // HBM latency hides under the staging DMA + barrier drain.
    int q0 = blockIdx.x * BLOCK + threadIdx.x;   // < 196608 < NQUADS always
    loadImg(img, q0, im0);
    int q1 = q0 + TSTRIDE;
    bool v1 = q1 < NQUADS;                       // block-uniform (140*768 cut)
    if (v1) loadImg(img, q1, im1);

    if (PACKED) {
        // global -> LDS DMA, 16B per lane per issue; destination is linear
        // (wave-uniform base + lane*16), which matches this layout exactly.
        constexpr int NCH = LUT_N / 4;     // 8984 16B chunks + 1 tail dword
        const int lane = threadIdx.x & 63;
        for (int c = threadIdx.x; c < NCH; c += BLOCK) {
            const unsigned int* gsrc = packed + c * 4;
            unsigned int* ldst = slut + (c - lane) * 4;   // wave-uniform base
            __builtin_amdgcn_global_load_lds(
                (const __attribute__((address_space(1))) unsigned int*)gsrc,
                (__attribute__((address_space(3))) unsigned int*)ldst,
                16, 0, 0);
        }
        if (threadIdx.x == 0) slut[LUT_N - 1] = packed[LUT_N - 1];
    } else {
        for (int i = threadIdx.x; i < LUT_N; i += BLOCK)
            slut[i] = quant3(lut[i], lut[i + LUT_N], lut[i + 2 * LUT_N]);
    }
    __syncthreads();   // drains vmcnt(0): staging DMA + im0/im1 all complete

    makeFrag(slut, im0, fg0);              // gathers for iter 0 in flight

    // steady state at body top (parity s): fg[s] gathered, im[s^1] holds
    // img for the next iter, load target im[s] is free.
    while (true) {
        {   // s = 0: blend fg0; produce fg1 from im1; load n+2 -> im0
            int q2 = q1 + TSTRIDE; bool v2 = q2 < NQUADS;
            if (v2) loadImg(img, q2, im0);
            if (v1) makeFrag(slut, im1, fg1);
            blendStore(fg0, out);
            if (!v1) return;
            q1 = q2; v1 = v2;
        }
        {   // s = 1: blend fg1; produce fg0 from im0; load n+2 -> im1
            int q2 = q1 + TSTRIDE; bool v2 = q2 < NQUADS;
            if (v2) loadImg(img, q2, im1);
            if (v1) makeFrag(slut, im0, fg0);
            blendStore(fg1, out);
            if (!v1) return;
            q1 = q2; v1 = v2;
        }
    }
}

extern "C" void kernel_launch(void* const* d_in, const int* in_sizes, int n_in,
                              void* d_out, int out_size, void* d_ws, size_t ws_size,
                              hipStream_t stream) {
    const float* lut = (const float*)d_in[0];
    const float* img = (const float*)d_in[1];
    float* out = (float*)d_out;

    if (ws_size >= (size_t)LUT_N * sizeof(unsigned int)) {
        unsigned int* packed = (unsigned int*)d_ws;
        quantize_lut_kernel<<<(LUT_N + 255) / 256, 256, 0, stream>>>(lut, packed);
        trilut_kernel<true><<<GRID, BLOCK, 0, stream>>>(lut, packed, img, out);
    } else {
        trilut_kernel<false><<<GRID, BLOCK, 0, stream>>>(lut, nullptr, img, out);
    }
}